// Round 7
// baseline (374.991 us; speedup 1.0000x reference)
//
#include <hip/hip_runtime.h>
#include <math.h>

#define B 1024
#define T 512
#define S 48
#define SOS 47

// broadcast lane l's value to all lanes via the SGPR file (VALU op)
__device__ __forceinline__ float rdlanef(float v, int l) {
    return __int_as_float(__builtin_amdgcn_readlane(__float_as_int(v), l));
}
// wave-uniform read of a value known equal across lanes
__device__ __forceinline__ float rdfirstf(float v) {
    return __int_as_float(__builtin_amdgcn_readfirstlane(__float_as_int(v)));
}

// ---------------------------------------------------------------------------
// Fused CRF loss. One wave per row; lane i owns state i; expT row in VGPRs.
// Scan kept in exp space with DELAYED normalization:
//   invariant  u_t = q * exp(M)   (exact; r_s == exp(-l_s) pending factor)
//   live step: q' = (expT q) * exp(emis - er) * r_s ;  M += er + l_s
//              then r_s = rcp(d1), l_s = log(d1)   [off critical chain]
//
// ROUND 7: attack the STEP-BOUNDARY DRAIN, not issue count.
// Evidence: r1 (48rl+48fma) = 145us @ VALUBusy 60%; r6 (48rl+24pk, ~20%
// fewer issue slots) = 149us @ 61%. Issue count is not binding; the ~40%
// idle is the serial joint: d tail -> qn -> v_cndmask -> readlane ->
// SGPR-read hazard -> first fma, paid 512 times with zero TLP (1 wave/SIMD).
// Changes (values provably identical to round 1 -> absmax 0.0):
//  1. Persistent wave-uniform sq[48] (SGPR-resident broadcast of q); the
//     dot's v_fma reads sq[j] as its one legal SGPR source. Transport is
//     no longer between select and fma.
//  2. PRE-SELECT readlanes: broadcast qn (unselected) right after qn=d*F;
//     the 48 readlanes no longer wait on the cndmask.
//  3. SCALAR select for masking: live is wave-uniform (mask is a per-row
//     scalar; readfirstlane -> s_cmp), so the 48 sq updates become
//     s_cselect_b32 on the SALU -- co-issued, zero VALU slots. The vector
//     q select (epilogue-only consumer) moves fully off-chain.
// Emission/mask prefetch double-buffered per 8-step block (unchanged).
// amdgpu_waves_per_eu(1): full VGPR budget (structurally 1 wave/SIMD).
// ---------------------------------------------------------------------------
__global__ __launch_bounds__(64, 1)
__attribute__((amdgpu_waves_per_eu(1)))
void crf_fused(const float* __restrict__ feat,
               const int* __restrict__ states,
               const float* __restrict__ mask,
               const float* __restrict__ trans,
               float* __restrict__ out) {
    const int b = blockIdx.x;
    const int lane = threadIdx.x;
    const int elane = (lane < S) ? lane : 0;    // lanes 48-63 shadow lane 0
    const float* f_b = feat + (size_t)b * T * S;
    const float* m_b = mask + b * T;
    const int* st_b = states + b * T;

    // ---- numerator (latency overlaps expT setup) ----
    float nsum = 0.f;
#pragma unroll
    for (int k2 = 0; k2 < T / 64; ++k2) {
        const int t = lane + k2 * 64;
        const int st = st_b[t];
        const int pv = (t == 0) ? SOS : st_b[t - 1];
        nsum += (f_b[t * S + st] + trans[st * S + pv]) * m_b[t];
    }

    // ---- expT row for this lane; exp(-9999) underflows to exact 0 ----
    float expT[S];
    {
        const float4* t4 = (const float4*)(trans + elane * S);
#pragma unroll
        for (int j4 = 0; j4 < S / 4; ++j4) {
            const float4 tv = t4[j4];
            expT[4 * j4 + 0] = (lane < S) ? __expf(tv.x) : 0.f;
            expT[4 * j4 + 1] = (lane < S) ? __expf(tv.y) : 0.f;
            expT[4 * j4 + 2] = (lane < S) ? __expf(tv.z) : 0.f;
            expT[4 * j4 + 3] = (lane < S) ? __expf(tv.w) : 0.f;
        }
    }

    // ---- scan state ----
    float q = (lane == SOS) ? 1.f : 0.f;        // vector copy: epilogue only
    float M = 0.f;
    float r_s = 1.f, l_s = 0.f;      // pending normalizer: r_s == exp(-l_s)

    // persistent wave-uniform broadcast of q, SGPR-resident
    float sq[S];
#pragma unroll
    for (int j = 0; j < S; ++j) sq[j] = (j == SOS) ? 1.f : 0.f;

    // emission/mask double-buffered block rings (8 steps per block)
    float ering[2][8], mring[2][8];
#pragma unroll
    for (int k = 0; k < 8; ++k) {
        ering[0][k] = f_b[k * S + elane];
        mring[0][k] = m_b[k];
    }

#pragma unroll 2
    for (int tb = 0; tb < T / 8; ++tb) {
        const int pb = tb & 1;
        // issue next block's loads now; consumed a full block later
        const int tn = ((tb + 1) & (T / 8 - 1)) * 8;   // wrap: last refill unused
#pragma unroll
        for (int k = 0; k < 8; ++k) {
            ering[pb ^ 1][k] = f_b[(tn + k) * S + elane];
            mring[pb ^ 1][k] = m_b[tn + k];
        }
#pragma unroll
        for (int k = 0; k < 8; ++k) {
            // off-chain: per-lane factor from prefetched emission
            const float emis = ering[pb][k];
            const float er = rdlanef(emis, 1);
            const float F = __expf(emis - er) * r_s;
            // chain: dot d_i = expT[i] . q with SGPR-resident sq[] --
            // v_fma reads sq[j] directly (1 SGPR source), no transport here
            float ax = 0.f, ay = 0.f, az = 0.f, aw = 0.f;
#pragma unroll
            for (int j4 = 0; j4 < S / 4; ++j4) {
                ax = fmaf(expT[4 * j4 + 0], sq[4 * j4 + 0], ax);
                ay = fmaf(expT[4 * j4 + 1], sq[4 * j4 + 1], ay);
                az = fmaf(expT[4 * j4 + 2], sq[4 * j4 + 2], az);
                aw = fmaf(expT[4 * j4 + 3], sq[4 * j4 + 3], aw);
            }
            const float d = (ax + ay) + (az + aw);
            const float qn = d * F;

            // wave-uniform liveness (mring holds the same scalar in every
            // lane); scalar compare -> SCC
            const bool live = (rdfirstf(mring[pb][k]) != 0.f);

            // PRE-SELECT broadcast: readlane qn immediately (not gated on
            // the vector select), then SALU s_cselect against old sq.
            // live: sq[j] = qn_j = q_j(t+1); !live: sq[j] keeps q_j(t).
            // Exactly round 1's values.
#pragma unroll
            for (int j = 0; j < S; ++j) {
                const float rlv = rdlanef(qn, j);
                sq[j] = live ? rlv : sq[j];
            }
            q = live ? qn : q;                  // off-chain, epilogue only

            // off-chain: next normalizer + shift bookkeeping
            M = live ? (M + er + l_s) : M;      // uses OLD l_s, then update
            const float dr = rdlanef(d, 1);     // lane1 dot: provably > 0
            const float nl = __logf(dr);
            const float nr = __builtin_amdgcn_rcpf(dr);
            r_s = live ? nr : r_s;
            l_s = live ? nl : l_s;
        }
    }

    // ---- epilogue: denom = M + log(sum_i q_i); out = denom - numer ----
    float ps = q;                               // lanes >= 48 hold 0
#pragma unroll
    for (int off = 32; off > 0; off >>= 1) {
        ps += __shfl_xor(ps, off, 64);
        nsum += __shfl_xor(nsum, off, 64);
    }
    if (lane == 0) out[b] = M + __logf(ps) - nsum;
}

extern "C" void kernel_launch(void* const* d_in, const int* in_sizes, int n_in,
                              void* d_out, int out_size, void* d_ws, size_t ws_size,
                              hipStream_t stream) {
    const float* feat   = (const float*)d_in[0];   // (B,T,S) f32
    const int*   states = (const int*)d_in[1];     // (B,T) i32
    const float* mask   = (const float*)d_in[2];   // (B,T) f32
    const float* trans  = (const float*)d_in[3];   // (S,S) f32
    float* out = (float*)d_out;                    // (B,) f32

    crf_fused<<<dim3(B), dim3(64), 0, stream>>>(feat, states, mask, trans, out);
}

// Round 8
// 253.745 us; speedup vs baseline: 1.4778x; 1.4778x over previous
//
#include <hip/hip_runtime.h>
#include <math.h>

#define B 1024
#define T 512
#define S 48
#define SOS 47

typedef float v2f __attribute__((ext_vector_type(2)));

// broadcast lane l's value to all lanes via the SGPR file (VALU op)
__device__ __forceinline__ float rdlanef(float v, int l) {
    return __int_as_float(__builtin_amdgcn_readlane(__float_as_int(v), l));
}

// ---------------------------------------------------------------------------
// Fused CRF loss. One wave per row; lane i owns state i; expT row in VGPRs.
// Scan kept in exp space with DELAYED normalization:
//   invariant  u_t = q * exp(M)   (exact; r_s == exp(-l_s) pending factor)
//   live step: q' = (expT q) * exp(emis - er) * r_s ;  M += er + l_s
//              then r_s = rcp(d1), l_s = log(d1)   [off critical chain]
//
// ROUND 8: BATCHED broadcast + pk_fma consume.
// Ledger: r1 (48rl+48fma inline)        145us  ~222 issue-cyc/step
//         r6 (pk, hard s[20:21]/unit)   149us  serialized units + 24x hazard
//         r7 (sq[]+per-elem select)     276us  sq went VGPR, +48 cndmask
// Consistent model: time = issue-count + LARGE stall term from the
// VALU-writes-SGPR -> VALU-reads-SGPR wait-state when each readlane is
// scheduled adjacent to its consuming fma (r1: paid up to 48x/step; r6:
// 24x INSIDE each asm unit + false serial chain through the one hard pair).
// Fix: per step, (1) batch all 48 readlanes first, packed into 24 u64
// (BUILD_PAIR -> aligned SGPR pairs, no SALU arithmetic), (2)
// sched_barrier(0) pins the separation, (3) dot = 24 v_pk_fma_f32 with the
// "s"-pair as src1 (r6 proved encoding + bitwise-identical pairing:
// accA=(ax,ay) <- pairs 2k = (q[4k],q[4k+1]); accB=(az,aw) <- pairs 2k+1).
// Hazard paid once (drained under F's exp), units independent -> pk stream
// pipelines, issue ~222 -> ~174 cyc/step.
// Select/bookkeeping/epilogue byte-identical to round 1 -> absmax 0.0.
// Emission/mask prefetch double-buffered per 8-step block (unchanged).
// amdgpu_waves_per_eu(1): full VGPR budget (structurally 1 wave/SIMD).
// ---------------------------------------------------------------------------
__global__ __launch_bounds__(64, 1)
__attribute__((amdgpu_waves_per_eu(1)))
void crf_fused(const float* __restrict__ feat,
               const int* __restrict__ states,
               const float* __restrict__ mask,
               const float* __restrict__ trans,
               float* __restrict__ out) {
    const int b = blockIdx.x;
    const int lane = threadIdx.x;
    const int elane = (lane < S) ? lane : 0;    // lanes 48-63 shadow lane 0
    const float* f_b = feat + (size_t)b * T * S;
    const float* m_b = mask + b * T;
    const int* st_b = states + b * T;

    // ---- numerator (latency overlaps expT setup) ----
    float nsum = 0.f;
#pragma unroll
    for (int k2 = 0; k2 < T / 64; ++k2) {
        const int t = lane + k2 * 64;
        const int st = st_b[t];
        const int pv = (t == 0) ? SOS : st_b[t - 1];
        nsum += (f_b[t * S + st] + trans[st * S + pv]) * m_b[t];
    }

    // ---- expT row for this lane, stored as aligned float2 pairs for
    //      v_pk_fma_f32; exp(-9999) underflows to exact 0 ----
    v2f expTp[S / 2];
    {
        const float4* t4 = (const float4*)(trans + elane * S);
#pragma unroll
        for (int j4 = 0; j4 < S / 4; ++j4) {
            const float4 tv = t4[j4];
            expTp[2 * j4 + 0].x = (lane < S) ? __expf(tv.x) : 0.f;
            expTp[2 * j4 + 0].y = (lane < S) ? __expf(tv.y) : 0.f;
            expTp[2 * j4 + 1].x = (lane < S) ? __expf(tv.z) : 0.f;
            expTp[2 * j4 + 1].y = (lane < S) ? __expf(tv.w) : 0.f;
        }
    }

    // ---- scan state ----
    float q = (lane == SOS) ? 1.f : 0.f;        // lanes >= 48 hold 0 forever
    float M = 0.f;
    float r_s = 1.f, l_s = 0.f;      // pending normalizer: r_s == exp(-l_s)

    // emission/mask double-buffered block rings (8 steps per block)
    float ering[2][8], mring[2][8];
#pragma unroll
    for (int k = 0; k < 8; ++k) {
        ering[0][k] = f_b[k * S + elane];
        mring[0][k] = m_b[k];
    }

#pragma unroll 2
    for (int tb = 0; tb < T / 8; ++tb) {
        const int pb = tb & 1;
        // issue next block's loads now; consumed a full block later
        const int tn = ((tb + 1) & (T / 8 - 1)) * 8;   // wrap: last refill unused
#pragma unroll
        for (int k = 0; k < 8; ++k) {
            ering[pb ^ 1][k] = f_b[(tn + k) * S + elane];
            mring[pb ^ 1][k] = m_b[tn + k];
        }
#pragma unroll
        for (int k = 0; k < 8; ++k) {
            // (1) BATCH: 48 readlanes -> 24 aligned SGPR pairs.
            // BUILD_PAIR of two uniform i32 -> REG_SEQUENCE (no SALU math).
            unsigned long long qp[S / 2];
#pragma unroll
            for (int m = 0; m < S / 2; ++m) {
                const unsigned lo =
                    (unsigned)__builtin_amdgcn_readlane(__float_as_int(q), 2 * m);
                const unsigned hi =
                    (unsigned)__builtin_amdgcn_readlane(__float_as_int(q), 2 * m + 1);
                qp[m] = ((unsigned long long)hi << 32) | lo;
            }
            __builtin_amdgcn_sched_barrier(0);   // pin batch/consume split

            // off-chain: per-lane factor from prefetched emission.
            // Runs here (after the barrier) and drains the readlane->SGPR
            // hazard window before the first pk_fma consumes a pair.
            const float emis = ering[pb][k];
            const float er = rdlanef(emis, 1);
            const float F = __expf(emis - er) * r_s;

            // (3) CONSUME: dot d_i = expT[i] . q as 24 v_pk_fma_f32.
            // accA=(ax,ay): pairs 2k = (q[4k],q[4k+1]);
            // accB=(az,aw): pairs 2k+1 = (q[4k+2],q[4k+3]).
            // First per chain: v_pk_mul == fma into 0.0 (bitwise).
            v2f accA, accB;
            asm("v_pk_mul_f32 %0, %1, %2"
                : "=&v"(accA) : "v"(expTp[0]), "s"(qp[0]));
            asm("v_pk_mul_f32 %0, %1, %2"
                : "=&v"(accB) : "v"(expTp[1]), "s"(qp[1]));
#pragma unroll
            for (int j4 = 1; j4 < S / 4; ++j4) {
                asm("v_pk_fma_f32 %0, %1, %2, %0"
                    : "+v"(accA) : "v"(expTp[2 * j4 + 0]), "s"(qp[2 * j4 + 0]));
                asm("v_pk_fma_f32 %0, %1, %2, %0"
                    : "+v"(accB) : "v"(expTp[2 * j4 + 1]), "s"(qp[2 * j4 + 1]));
            }
            const float d = (accA.x + accA.y) + (accB.x + accB.y);
            const float qn = d * F;
            const bool live = (mring[pb][k] != 0.f);
            q = live ? qn : q;                  // SELECT, never blend
            // off-chain: next normalizer + shift bookkeeping
            M = live ? (M + er + l_s) : M;      // uses OLD l_s, then update
            const float dr = rdlanef(d, 1);     // lane1 dot: provably > 0
            const float nl = __logf(dr);
            const float nr = __builtin_amdgcn_rcpf(dr);
            r_s = live ? nr : r_s;
            l_s = live ? nl : l_s;
        }
    }

    // ---- epilogue: denom = M + log(sum_i q_i); out = denom - numer ----
    float ps = q;                               // lanes >= 48 hold 0
#pragma unroll
    for (int off = 32; off > 0; off >>= 1) {
        ps += __shfl_xor(ps, off, 64);
        nsum += __shfl_xor(nsum, off, 64);
    }
    if (lane == 0) out[b] = M + __logf(ps) - nsum;
}

extern "C" void kernel_launch(void* const* d_in, const int* in_sizes, int n_in,
                              void* d_out, int out_size, void* d_ws, size_t ws_size,
                              hipStream_t stream) {
    const float* feat   = (const float*)d_in[0];   // (B,T,S) f32
    const int*   states = (const int*)d_in[1];     // (B,T) i32
    const float* mask   = (const float*)d_in[2];   // (B,T) f32
    const float* trans  = (const float*)d_in[3];   // (S,S) f32
    float* out = (float*)d_out;                    // (B,) f32

    crf_fused<<<dim3(B), dim3(64), 0, stream>>>(feat, states, mask, trans, out);
}